// Round 10
// baseline (137.062 us; speedup 1.0000x reference)
//
#include <hip/hip_runtime.h>

#define B 16
typedef float f32x4 __attribute__((ext_vector_type(4)));

// pw layout: .x = bit-packed indices (i0 | i1<<10 | i2<<20), .y/.z/.w = weights
__device__ __forceinline__ void unpack_pw(const f32x4 pw, int& i0, int& i1, int& i2) {
    unsigned p = __float_as_uint(pw[0]);
    i0 = p & 1023; i1 = (p >> 10) & 1023; i2 = p >> 20;
}

// ---------------- top-3 helpers (tie-break: earliest index) ----------------
struct Top3 { float d0, d1, d2; int i0, i1, i2; };

__device__ __forceinline__ void t3_init(Top3& s) {
    s.d0 = 1e30f; s.d1 = 1e30f; s.d2 = 1e30f; s.i0 = -1; s.i1 = -1; s.i2 = -1;
}
// ascending-j scan: strict < keeps earliest index on ties
__device__ __forceinline__ void t3_scan(Top3& s, float d, int j) {
    if (d < s.d2) {
        if (d < s.d1) {
            s.d2 = s.d1; s.i2 = s.i1;
            if (d < s.d0) { s.d1 = s.d0; s.i1 = s.i0; s.d0 = d; s.i0 = j; }
            else          { s.d1 = d;  s.i1 = j; }
        } else { s.d2 = d; s.i2 = j; }
    }
}
__device__ __forceinline__ void t3_merge(Top3& s, float d, int j) {
    if (d < s.d0 || (d == s.d0 && j < s.i0)) {
        s.d2 = s.d1; s.i2 = s.i1; s.d1 = s.d0; s.i1 = s.i0; s.d0 = d; s.i0 = j;
    } else if (d < s.d1 || (d == s.d1 && j < s.i1)) {
        s.d2 = s.d1; s.i2 = s.i1; s.d1 = d; s.i1 = j;
    } else if (d < s.d2 || (d == s.d2 && j < s.i2)) {
        s.d2 = d; s.i2 = j;
    }
}
__device__ __forceinline__ void t3_shfl_merge(Top3& s, int r) {
    float e0 = __shfl_xor(s.d0, r), e1 = __shfl_xor(s.d1, r), e2 = __shfl_xor(s.d2, r);
    int   j0 = __shfl_xor(s.i0, r), j1 = __shfl_xor(s.i1, r), j2 = __shfl_xor(s.i2, r);
    t3_merge(s, e0, j0); t3_merge(s, e1, j1); t3_merge(s, e2, j2);
}
__device__ __forceinline__ f32x4 t3_finalize(const Top3& s) {
    float w0 = 1.0f / (s.d0 + 1e-8f);
    float w1 = 1.0f / (s.d1 + 1e-8f);
    float w2 = 1.0f / (s.d2 + 1e-8f);
    float inv = 1.0f / (w0 + w1 + w2);
    unsigned packed = (unsigned)s.i0 | ((unsigned)s.i1 << 10) | ((unsigned)s.i2 << 20);
    f32x4 r = {__uint_as_float(packed), w0 * inv, w1 * inv, w2 * inv};
    return r;
}

// ===================== fused 4-stage 3-NN + f0 copy =====================
// [0,512): stage3 PP=2 (4096 pts, 32 blk/batch); [512,640): stage2 PP=2
// (1024 pts, 8 blk/batch); [640,704): stage1 PP=1; [704,720): stage0 PP=1;
// [720,848): f0 -> out copy (overlaps HBM under the knn scan).
// PP=2: each thread's ds_read_b128 of a coarse point feeds TWO fine points'
// distance ladders -> stage-3 LDS instruction count halves (the knn gate).
__global__ __launch_bounds__(256) void knn_all_kernel(
    const float* __restrict__ xyz0, const float* __restrict__ xyz1,
    const float* __restrict__ xyz2, const float* __restrict__ xyz3,
    const float* __restrict__ xyz4, const float* __restrict__ f0,
    float* __restrict__ out,
    f32x4* pw0, f32x4* pw1, f32x4* pw2, f32x4* pw3) {
    __shared__ float lds[(256 + 1) * 4 * 4];  // 4 segs x (S4max+1) x {x,y,z,|b|2}
    int bid = blockIdx.x;
    if (bid >= 720) {  // f0 copy: 8-channel chunk, nontemporal streaming
        bid -= 720;
        const int b = bid >> 3;
        const int c0 = (bid & 7) * 8;
        const f32x4* src = reinterpret_cast<const f32x4*>(f0 + ((size_t)b * 64 + c0) * 4096);
        f32x4* dst = reinterpret_cast<f32x4*>(out + ((size_t)b * 1984 + c0) * 4096);
        for (int i = threadIdx.x; i < 8 * 1024; i += 256) {
            __builtin_nontemporal_store(__builtin_nontemporal_load(src + i), dst + i);
        }
        return;
    }
    int S, logS4, N, b, nblk;
    bool pp2;
    const float *xf, *xc;
    f32x4* po;
    if (bid < 512)      { pp2 = true;  S = 1024; logS4 = 8; N = 4096; xf = xyz0; xc = xyz1; po = pw3; b = bid >> 5; nblk = bid & 31; }
    else if (bid < 640) { pp2 = true;  S = 256;  logS4 = 6; N = 1024; xf = xyz1; xc = xyz2; po = pw2; int z = bid - 512; b = z >> 3; nblk = z & 7; }
    else if (bid < 704) { pp2 = false; S = 64;   logS4 = 4; N = 256;  xf = xyz2; xc = xyz3; po = pw1; int z = bid - 640; b = z >> 2; nblk = z & 3; }
    else                { pp2 = false; S = 16;   logS4 = 2; N = 64;   xf = xyz3; xc = xyz4; po = pw0; b = bid - 704; nblk = 0; }
    const int S4 = S >> 2;

    const float* cbase = xc + (size_t)b * S * 3;
    for (int j = threadIdx.x; j < S; j += 256) {
        float x = cbase[j * 3 + 0], y = cbase[j * 3 + 1], z = cbase[j * 3 + 2];
        int seg = j >> logS4, jj = j & (S4 - 1);
        float* p = lds + (size_t)(seg * (S4 + 1) + jj) * 4;
        p[0] = x; p[1] = y; p[2] = z; p[3] = x * x + y * y + z * z;
    }
    __syncthreads();
    const int t = threadIdx.x;
    const int sub = t & 3;
    const f32x4* seg4 = reinterpret_cast<const f32x4*>(lds) + sub * (S4 + 1);
    const int jbase = sub * S4;

    if (pp2) {
        const int n0 = nblk * 128 + (t >> 2) * 2;  // two points: n0, n0+1
        const float2* fp2 = reinterpret_cast<const float2*>(xf + ((size_t)b * N + n0) * 3);
        float2 qa = fp2[0], qb = fp2[1], qc = fp2[2];
        const float ax0 = qa.x, ay0 = qa.y, az0 = qb.x;
        const float ax1 = qb.y, ay1 = qc.x, az1 = qc.y;
        const float an0 = ax0 * ax0 + ay0 * ay0 + az0 * az0;
        const float an1 = ax1 * ax1 + ay1 * ay1 + az1 * az1;
        Top3 sA, sB; t3_init(sA); t3_init(sB);
#pragma unroll 4
        for (int k = 0; k < S4; ++k) {
            f32x4 c = seg4[k];
            int j = jbase + k;
            float dA = an0 + c[3] - 2.0f * (ax0 * c[0] + ay0 * c[1] + az0 * c[2]);
            float dB = an1 + c[3] - 2.0f * (ax1 * c[0] + ay1 * c[1] + az1 * c[2]);
            t3_scan(sA, dA, j);
            t3_scan(sB, dB, j);
        }
        t3_shfl_merge(sA, 1); t3_shfl_merge(sA, 2);
        t3_shfl_merge(sB, 1); t3_shfl_merge(sB, 2);
        if (sub == 0) {
            po[(size_t)b * N + n0]     = t3_finalize(sA);
            po[(size_t)b * N + n0 + 1] = t3_finalize(sB);
        }
    } else {
        const int n = nblk * 64 + (t >> 2);
        const float* fp = xf + ((size_t)b * N + n) * 3;
        const float ax = fp[0], ay = fp[1], az = fp[2];
        const float an2 = ax * ax + ay * ay + az * az;
        Top3 s; t3_init(s);
#pragma unroll 4
        for (int k = 0; k < S4; ++k) {
            f32x4 c = seg4[k];
            float d = an2 + c[3] - 2.0f * (ax * c[0] + ay * c[1] + az * c[2]);
            t3_scan(s, d, jbase + k);
        }
        t3_shfl_merge(s, 1); t3_shfl_merge(s, 2);
        if (sub == 0) po[(size_t)b * N + n] = t3_finalize(s);
    }
}

// ===================== decode mega-kernel =====================
// Block = (batch, 8-channel chunk). Expand level-by-level in LDS (f32x4
// planes, 4 channels each), final interp (pw3) streamed to d_out (nt stores).
// LDS union, exactly 40 KB -> 4 blocks/CU:
//   s3 = buf[0..2048)    s2 = buf[2048..2560)
//   s1 = buf[0..128) alias (dead before s3 written)   s0 = buf[128..160) alias

template <int P>
__device__ __forceinline__ void copy_planes(const float* __restrict__ src_rows,
                                            f32x4* dst, int t) {
    constexpr int P4 = P / 4;
    const f32x4* src = reinterpret_cast<const f32x4*>(src_rows);
    float* df = reinterpret_cast<float*>(dst);
    for (int e = t; e < 8 * P4; e += 256) {
        int c = e / P4;
        int s4 = e & (P4 - 1);
        f32x4 v = src[c * P4 + s4];
        int base = (((c >> 2) * P + s4 * 4) << 2) + (c & 3);
        df[base + 0] = v[0]; df[base + 4] = v[1];
        df[base + 8] = v[2]; df[base + 12] = v[3];
    }
}

template <int PD, int PS>
__device__ __forceinline__ void expand(const f32x4* src, f32x4* dst,
                                       const f32x4* __restrict__ pwL,
                                       int b, int t) {
    for (int e = t; e < 2 * PD; e += 256) {
        int p = (e >= PD) ? 1 : 0;
        int s = e - p * PD;
        f32x4 pw = pwL[(size_t)b * PD + s];
        int i0, i1, i2; unpack_pw(pw, i0, i1, i2);
        const f32x4* sp = src + p * PS;
        dst[e] = pw[1] * sp[i0] + pw[2] * sp[i1] + pw[3] * sp[i2];
    }
}

__global__ __launch_bounds__(256) void decode_kernel(
    const float* __restrict__ f1, const float* __restrict__ f2,
    const float* __restrict__ f3, const float* __restrict__ f4,
    const f32x4* __restrict__ pw0, const f32x4* __restrict__ pw1,
    const f32x4* __restrict__ pw2, const f32x4* __restrict__ pw3,
    float* __restrict__ out) {
    __shared__ f32x4 buf[2560];  // 40 KB exactly
    f32x4* s3 = buf;
    f32x4* s2 = buf + 2048;
    f32x4* s1 = buf;        // alias (dead before s3 written)
    f32x4* s0 = buf + 128;  // alias
    const int b = blockIdx.x;
    // heavy-first order: y=0 -> deepest chunk (cx largest)
    const int cx = (239 - blockIdx.y) * 8;  // [0,1920)
    const int t = threadIdx.x;
    float* outb = out + ((size_t)b * 1984 + 64 + cx) * 4096;

    if (cx < 128) {          // depth 1: source f1
        copy_planes<1024>(f1 + ((size_t)b * 128 + cx) * 1024, s3, t);
        __syncthreads();
    } else if (cx < 384) {   // depth 2: source f2
        copy_planes<256>(f2 + ((size_t)b * 256 + (cx - 128)) * 256, s2, t);
        __syncthreads();
        expand<1024, 256>(s2, s3, pw2, b, t);
        __syncthreads();
    } else if (cx < 896) {   // depth 3: source f3
        copy_planes<64>(f3 + ((size_t)b * 512 + (cx - 384)) * 64, s1, t);
        __syncthreads();
        expand<256, 64>(s1, s2, pw1, b, t);
        __syncthreads();
        expand<1024, 256>(s2, s3, pw2, b, t);
        __syncthreads();
    } else {                 // depth 4: source f4
        copy_planes<16>(f4 + ((size_t)b * 1024 + (cx - 896)) * 16, s0, t);
        __syncthreads();
        expand<64, 16>(s0, s1, pw0, b, t);   // s0 (buf+128) -> s1 (buf+0)
        __syncthreads();
        expand<256, 64>(s1, s2, pw1, b, t);
        __syncthreads();
        expand<1024, 256>(s2, s3, pw2, b, t);
        __syncthreads();
    }
    // final: 4096 fine points via pw3; f32x4 nontemporal stores along n
    const f32x4* pwF = pw3 + (size_t)b * 4096;
#pragma unroll 2
    for (int it = 0; it < 4; ++it) {
        const int n0 = (it * 256 + t) * 4;
        f32x4 pwv[4];
#pragma unroll
        for (int q = 0; q < 4; ++q) pwv[q] = pwF[n0 + q];
#pragma unroll
        for (int p = 0; p < 2; ++p) {
            const f32x4* pl = s3 + p * 1024;
            f32x4 v[4];
#pragma unroll
            for (int q = 0; q < 4; ++q) {
                int i0, i1, i2; unpack_pw(pwv[q], i0, i1, i2);
                v[q] = pwv[q][1] * pl[i0] + pwv[q][2] * pl[i1] + pwv[q][3] * pl[i2];
            }
            float* ob = outb + (size_t)(p * 4) * 4096 + n0;
#pragma unroll
            for (int j = 0; j < 4; ++j) {
                f32x4 st = {v[0][j], v[1][j], v[2][j], v[3][j]};
                __builtin_nontemporal_store(st, reinterpret_cast<f32x4*>(ob + (size_t)j * 4096));
            }
        }
    }
}

extern "C" void kernel_launch(void* const* d_in, const int* in_sizes, int n_in,
                              void* d_out, int out_size, void* d_ws, size_t ws_size,
                              hipStream_t stream) {
    static const int xyzSz[5] = {16 * 4096 * 3, 16 * 1024 * 3, 16 * 256 * 3,
                                 16 * 64 * 3, 16 * 16 * 3};
    static const int fSz[5] = {16 * 64 * 4096, 16 * 128 * 1024, 16 * 256 * 256,
                               16 * 512 * 64, 16 * 1024 * 16};
    const float* xyz[5] = {nullptr, nullptr, nullptr, nullptr, nullptr};
    const float* f[5] = {nullptr, nullptr, nullptr, nullptr, nullptr};
    for (int i = 0; i < n_in; ++i) {
        for (int j = 0; j < 5; ++j) {
            if (in_sizes[i] == xyzSz[j] && !xyz[j]) { xyz[j] = (const float*)d_in[i]; goto next; }
            if (in_sizes[i] == fSz[j] && !f[j])     { f[j] = (const float*)d_in[i];  goto next; }
        }
    next:;
    }

    // ws: packed idx+w per stage (1.34 MB total, L2-resident)
    char* ws = (char*)d_ws;
    f32x4* pw3 = (f32x4*)(ws);                       // 1 MiB
    f32x4* pw2 = (f32x4*)(ws + (1u << 20));          // 256 KiB
    f32x4* pw1 = (f32x4*)(ws + (1u << 20) + 262144u);   // 64 KiB
    f32x4* pw0 = (f32x4*)(ws + (1u << 20) + 327680u);   // 16 KiB

    knn_all_kernel<<<848, 256, 0, stream>>>(
        xyz[0], xyz[1], xyz[2], xyz[3], xyz[4], f[0], (float*)d_out,
        pw0, pw1, pw2, pw3);

    decode_kernel<<<dim3(B, 240), 256, 0, stream>>>(
        f[1], f[2], f[3], f[4], pw0, pw1, pw2, pw3, (float*)d_out);
}

// Round 11
// 131.691 us; speedup vs baseline: 1.0408x; 1.0408x over previous
//
#include <hip/hip_runtime.h>

#define B 16
typedef float f32x4 __attribute__((ext_vector_type(4)));

// ===================== fused 4-stage 3-NN + f0 copy =====================
// Blocks [0,1024): stage3; [1024,1280): stage2; [1280,1344): stage1;
// [1344,1360): stage0; [1360,1616): f0 -> out copy (4-ch chunks so all CUs
// stream the copy while knn blocks run their VALU-bound scan).
__global__ __launch_bounds__(256) void knn_all_kernel(
    const float* __restrict__ xyz0, const float* __restrict__ xyz1,
    const float* __restrict__ xyz2, const float* __restrict__ xyz3,
    const float* __restrict__ xyz4, const float* __restrict__ f0,
    float* __restrict__ out,
    int4* idx0, float4* w0, int4* idx1, float4* w1,
    int4* idx2, float4* w2, int4* idx3, float4* w3) {
    __shared__ float lds[(256 + 1) * 4 * 4];  // 4 segs x (S4max+1) x {x,y,z,|b|2}
    int bid = blockIdx.x;
    if (bid >= 1360) {  // f0 copy: 4-channel chunk, nontemporal streaming
        bid -= 1360;
        const int b = bid >> 4;
        const int c0 = (bid & 15) * 4;
        const f32x4* src = reinterpret_cast<const f32x4*>(f0 + ((size_t)b * 64 + c0) * 4096);
        f32x4* dst = reinterpret_cast<f32x4*>(out + ((size_t)b * 1984 + c0) * 4096);
        for (int i = threadIdx.x; i < 4 * 1024; i += 256) {
            __builtin_nontemporal_store(__builtin_nontemporal_load(src + i), dst + i);
        }
        return;
    }
    int S, logS4;
    const float *xf, *xc;
    int4* io; float4* wo;
    if (bid < 1024)      { S = 1024; logS4 = 8; xf = xyz0; xc = xyz1; io = idx3; wo = w3; }
    else if (bid < 1280) { bid -= 1024; S = 256; logS4 = 6; xf = xyz1; xc = xyz2; io = idx2; wo = w2; }
    else if (bid < 1344) { bid -= 1280; S = 64;  logS4 = 4; xf = xyz2; xc = xyz3; io = idx1; wo = w1; }
    else                 { bid -= 1344; S = 16;  logS4 = 2; xf = xyz3; xc = xyz4; io = idx0; wo = w0; }
    const int N = S << 2;
    const int lognb = logS4 - 2;              // nb = N/64 = S/16
    const int b = bid >> lognb;
    const int nblk = bid & ((1 << lognb) - 1);
    const int S4 = S >> 2;

    const float* cbase = xc + (size_t)b * S * 3;
    for (int j = threadIdx.x; j < S; j += 256) {
        float x = cbase[j * 3 + 0], y = cbase[j * 3 + 1], z = cbase[j * 3 + 2];
        int seg = j >> logS4, jj = j & (S4 - 1);
        float* p = lds + (size_t)(seg * (S4 + 1) + jj) * 4;
        p[0] = x; p[1] = y; p[2] = z; p[3] = x * x + y * y + z * z;
    }
    __syncthreads();
    const int t = threadIdx.x;
    const int sub = t & 3;
    const int n = nblk * 64 + (t >> 2);
    const float* fp = xf + ((size_t)b * N + n) * 3;
    const float ax = fp[0], ay = fp[1], az = fp[2];
    const float an2 = ax * ax + ay * ay + az * az;
    float d0 = 1e30f, d1 = 1e30f, d2 = 1e30f;
    int i0 = -1, i1 = -1, i2 = -1;
    const f32x4* seg4 = reinterpret_cast<const f32x4*>(lds) + sub * (S4 + 1);
    const int jbase = sub * S4;
#pragma unroll 4
    for (int k = 0; k < S4; ++k) {
        f32x4 c = seg4[k];
        float d = an2 + c[3] - 2.0f * (ax * c[0] + ay * c[1] + az * c[2]);
        int j = jbase + k;
        if (d < d2) {  // ascending j: strict < keeps earliest index on ties
            if (d < d1) {
                d2 = d1; i2 = i1;
                if (d < d0) { d1 = d0; i1 = i0; d0 = d; i0 = j; }
                else        { d1 = d;  i1 = j; }
            } else { d2 = d; i2 = j; }
        }
    }
#pragma unroll
    for (int r = 1; r <= 2; r <<= 1) {
        float e0 = __shfl_xor(d0, r), e1 = __shfl_xor(d1, r), e2 = __shfl_xor(d2, r);
        int   j0 = __shfl_xor(i0, r), j1 = __shfl_xor(i1, r), j2 = __shfl_xor(i2, r);
        float ed[3] = {e0, e1, e2};
        int   ej[3] = {j0, j1, j2};
#pragma unroll
        for (int m = 0; m < 3; ++m) {
            float d = ed[m]; int j = ej[m];
            if (d < d0 || (d == d0 && j < i0)) {
                d2 = d1; i2 = i1; d1 = d0; i1 = i0; d0 = d; i0 = j;
            } else if (d < d1 || (d == d1 && j < i1)) {
                d2 = d1; i2 = i1; d1 = d; i1 = j;
            } else if (d < d2 || (d == d2 && j < i2)) {
                d2 = d; i2 = j;
            }
        }
    }
    if (sub == 0) {
        float w0_ = 1.0f / (d0 + 1e-8f);
        float w1_ = 1.0f / (d1 + 1e-8f);
        float w2_ = 1.0f / (d2 + 1e-8f);
        float inv = 1.0f / (w0_ + w1_ + w2_);
        size_t o = (size_t)b * N + n;
        io[o] = make_int4(i0, i1, i2, 0);
        wo[o] = make_float4(w0_ * inv, w1_ * inv, w2_ * inv, 0.0f);
    }
}

// ===================== decode mega-kernel =====================
// Block = (batch, 8-channel chunk of the interpolated region). Lineage is a
// single source level; expand level-by-level in LDS (4-channel f32x4 planes),
// then final interp (idx3) streamed to d_out with nontemporal stores.
// LDS union (exactly 40 KB -> 4 blocks/CU):
//   s3 = buf[0..2048)       (32 KB, final 2 planes x 1024)
//   s2 = buf[2048..2560)    (8 KB)
//   s1 = buf[0..128)        (aliases s3 area; dead before s3 is written)
//   s0 = buf[128..160)      (aliases s3 area; dead before s1 consumed it)

template <int P>
__device__ __forceinline__ void copy_planes(const float* __restrict__ src_rows,
                                            f32x4* dst, int t) {
    constexpr int P4 = P / 4;
    const f32x4* src = reinterpret_cast<const f32x4*>(src_rows);
    float* df = reinterpret_cast<float*>(dst);
    for (int e = t; e < 8 * P4; e += 256) {
        int c = e / P4;
        int s4 = e & (P4 - 1);
        f32x4 v = src[c * P4 + s4];
        int base = (((c >> 2) * P + s4 * 4) << 2) + (c & 3);
        df[base + 0] = v[0]; df[base + 4] = v[1];
        df[base + 8] = v[2]; df[base + 12] = v[3];
    }
}

template <int PD, int PS>
__device__ __forceinline__ void expand(const f32x4* src, f32x4* dst,
                                       const int4* __restrict__ idxL,
                                       const f32x4* __restrict__ wL,
                                       int b, int t) {
    for (int e = t; e < 2 * PD; e += 256) {
        int p = (e >= PD) ? 1 : 0;
        int s = e - p * PD;
        int4 id = idxL[(size_t)b * PD + s];
        f32x4 ww = wL[(size_t)b * PD + s];
        const f32x4* sp = src + p * PS;
        dst[e] = ww[0] * sp[id.x] + ww[1] * sp[id.y] + ww[2] * sp[id.z];
    }
}

__global__ __launch_bounds__(256) void decode_kernel(
    const float* __restrict__ f1, const float* __restrict__ f2,
    const float* __restrict__ f3, const float* __restrict__ f4,
    const int4* __restrict__ idx0, const f32x4* __restrict__ w0,
    const int4* __restrict__ idx1, const f32x4* __restrict__ w1,
    const int4* __restrict__ idx2, const f32x4* __restrict__ w2,
    const int4* __restrict__ idx3, const f32x4* __restrict__ w3,
    float* __restrict__ out) {
    __shared__ f32x4 buf[2560];  // 40 KB exactly
    f32x4* s3 = buf;
    f32x4* s2 = buf + 2048;
    f32x4* s1 = buf;        // alias (dead before s3 written)
    f32x4* s0 = buf + 128;  // alias
    const int b = blockIdx.x;
    // heavy-first order: y=0 -> deepest chunk (cx largest)
    const int cx = (239 - blockIdx.y) * 8;  // [0,1920), interpolated channels
    const int t = threadIdx.x;
    float* outb = out + ((size_t)b * 1984 + 64 + cx) * 4096;

    if (cx < 128) {          // depth 1: source f1
        copy_planes<1024>(f1 + ((size_t)b * 128 + cx) * 1024, s3, t);
        __syncthreads();
    } else if (cx < 384) {   // depth 2: source f2
        copy_planes<256>(f2 + ((size_t)b * 256 + (cx - 128)) * 256, s2, t);
        __syncthreads();
        expand<1024, 256>(s2, s3, idx2, w2, b, t);
        __syncthreads();
    } else if (cx < 896) {   // depth 3: source f3
        copy_planes<64>(f3 + ((size_t)b * 512 + (cx - 384)) * 64, s1, t);
        __syncthreads();
        expand<256, 64>(s1, s2, idx1, w1, b, t);
        __syncthreads();
        expand<1024, 256>(s2, s3, idx2, w2, b, t);
        __syncthreads();
    } else {                 // depth 4: source f4
        copy_planes<16>(f4 + ((size_t)b * 1024 + (cx - 896)) * 16, s0, t);
        __syncthreads();
        expand<64, 16>(s0, s1, idx0, w0, b, t);   // s0 (buf+128) -> s1 (buf+0)
        __syncthreads();
        expand<256, 64>(s1, s2, idx1, w1, b, t);
        __syncthreads();
        expand<1024, 256>(s2, s3, idx2, w2, b, t);
        __syncthreads();
    }
    // final level: 4096 fine points via idx3/w3, f32x4 nontemporal stores
    const int4* idxF = idx3 + (size_t)b * 4096;
    const f32x4* wF = w3 + (size_t)b * 4096;
#pragma unroll 2
    for (int it = 0; it < 4; ++it) {
        const int n0 = (it * 256 + t) * 4;
        int4 id[4]; f32x4 ww[4];
#pragma unroll
        for (int q = 0; q < 4; ++q) { id[q] = idxF[n0 + q]; ww[q] = wF[n0 + q]; }
#pragma unroll
        for (int p = 0; p < 2; ++p) {
            const f32x4* pl = s3 + p * 1024;
            f32x4 v[4];
#pragma unroll
            for (int q = 0; q < 4; ++q) {
                v[q] = ww[q][0] * pl[id[q].x] + ww[q][1] * pl[id[q].y]
                     + ww[q][2] * pl[id[q].z];
            }
            float* ob = outb + (size_t)(p * 4) * 4096 + n0;
#pragma unroll
            for (int j = 0; j < 4; ++j) {
                f32x4 st = {v[0][j], v[1][j], v[2][j], v[3][j]};
                __builtin_nontemporal_store(st, reinterpret_cast<f32x4*>(ob + (size_t)j * 4096));
            }
        }
    }
}

extern "C" void kernel_launch(void* const* d_in, const int* in_sizes, int n_in,
                              void* d_out, int out_size, void* d_ws, size_t ws_size,
                              hipStream_t stream) {
    static const int xyzSz[5] = {16 * 4096 * 3, 16 * 1024 * 3, 16 * 256 * 3,
                                 16 * 64 * 3, 16 * 16 * 3};
    static const int fSz[5] = {16 * 64 * 4096, 16 * 128 * 1024, 16 * 256 * 256,
                               16 * 512 * 64, 16 * 1024 * 16};
    const float* xyz[5] = {nullptr, nullptr, nullptr, nullptr, nullptr};
    const float* f[5] = {nullptr, nullptr, nullptr, nullptr, nullptr};
    for (int i = 0; i < n_in; ++i) {
        for (int j = 0; j < 5; ++j) {
            if (in_sizes[i] == xyzSz[j] && !xyz[j]) { xyz[j] = (const float*)d_in[i]; goto next; }
            if (in_sizes[i] == fSz[j] && !f[j])     { f[j] = (const float*)d_in[i];  goto next; }
        }
    next:;
    }

    // ws layout (per-stage idx/w; ~2.7 MB, L2-resident)
    char* ws = (char*)d_ws;
    int4*   idx3 = (int4*)(ws);                       // 1 MiB
    float4* w3   = (float4*)(ws + (1u << 20));        // 1 MiB
    int4*   idx2 = (int4*)(ws + (2u << 20));          // 256 KiB
    float4* w2   = (float4*)(ws + (2u << 20) + 262144u);
    int4*   idx1 = (int4*)(ws + (2u << 20) + 524288u);   // 64 KiB
    float4* w1   = (float4*)(ws + (2u << 20) + 589824u);
    int4*   idx0 = (int4*)(ws + (2u << 20) + 655360u);   // 16 KiB
    float4* w0   = (float4*)(ws + (2u << 20) + 671744u);

    knn_all_kernel<<<1616, 256, 0, stream>>>(
        xyz[0], xyz[1], xyz[2], xyz[3], xyz[4], f[0], (float*)d_out,
        idx0, w0, idx1, w1, idx2, w2, idx3, w3);

    decode_kernel<<<dim3(B, 240), 256, 0, stream>>>(
        f[1], f[2], f[3], f[4],
        idx0, (const f32x4*)w0, idx1, (const f32x4*)w1,
        idx2, (const f32x4*)w2, idx3, (const f32x4*)w3,
        (float*)d_out);
}